// Round 1
// baseline (4738.950 us; speedup 1.0000x reference)
//
#include <hip/hip_runtime.h>

#define DDIM 80
#define PLANE (DDIM * DDIM)          // 6400
#define VOL   (DDIM * DDIM * DDIM)   // 512000
#define HALFV 4                      // volumes per input (b*c = 2*2)
#define NVOL  8                      // x volumes + y volumes
#define NTOT  (NVOL * VOL)           // 4,096,000

__device__ __forceinline__ void decomp(int idx, int& v, int& r, int& z, int& yy, int& xx) {
    v = idx / VOL;
    r = idx - v * VOL;
    z = r / PLANE;
    int r2 = r - z * PLANE;
    yy = r2 / DDIM;
    xx = r2 - yy * DDIM;
}

// e = erode(img) where img lives in the two input tensors (x volumes 0..3, y volumes 4..7)
__global__ void erode_first_k(const float* __restrict__ x, const float* __restrict__ y,
                              float* __restrict__ e) {
    int idx = blockIdx.x * blockDim.x + threadIdx.x;
    int v, r, z, yy, xx;
    decomp(idx, v, r, z, yy, xx);
    const float* __restrict__ src = (v < HALFV) ? (x + v * VOL) : (y + (v - HALFV) * VOL);
    float m = src[r];
    if (z > 0)         m = fminf(m, src[r - PLANE]);
    if (z < DDIM - 1)  m = fminf(m, src[r + PLANE]);
    if (yy > 0)        m = fminf(m, src[r - DDIM]);
    if (yy < DDIM - 1) m = fminf(m, src[r + DDIM]);
    if (xx > 0)        m = fminf(m, src[r - 1]);
    if (xx < DDIM - 1) m = fminf(m, src[r + 1]);
    e[idx] = m;
}

// e = erode(a), a is the full 8-volume buffer
__global__ void erode_step_k(const float* __restrict__ a, float* __restrict__ e) {
    int idx = blockIdx.x * blockDim.x + threadIdx.x;
    int v, r, z, yy, xx;
    decomp(idx, v, r, z, yy, xx);
    float m = a[idx];
    if (z > 0)         m = fminf(m, a[idx - PLANE]);
    if (z < DDIM - 1)  m = fminf(m, a[idx + PLANE]);
    if (yy > 0)        m = fminf(m, a[idx - DDIM]);
    if (yy < DDIM - 1) m = fminf(m, a[idx + DDIM]);
    if (xx > 0)        m = fminf(m, a[idx - 1]);
    if (xx < DDIM - 1) m = fminf(m, a[idx + 1]);
    e[idx] = m;
}

// delta = relu(img - dilate(e)); FIRST: skel = delta; else skel += relu(delta - skel*delta)
template <bool FIRST>
__global__ void dilate_update_k(const float* __restrict__ x, const float* __restrict__ y,
                                const float* __restrict__ a, const float* __restrict__ e,
                                float* __restrict__ skel) {
    int idx = blockIdx.x * blockDim.x + threadIdx.x;
    int v, r, z, yy, xx;
    decomp(idx, v, r, z, yy, xx);

    int z0 = (z > 0) ? z - 1 : 0,          z1 = (z < DDIM - 1) ? z + 1 : DDIM - 1;
    int y0 = (yy > 0) ? yy - 1 : 0,        y1 = (yy < DDIM - 1) ? yy + 1 : DDIM - 1;
    int x0 = (xx > 0) ? xx - 1 : 0,        x1 = (xx < DDIM - 1) ? xx + 1 : DDIM - 1;

    const float* __restrict__ ev = e + v * VOL;
    float m = -1e30f;
    for (int zz = z0; zz <= z1; ++zz) {
        for (int yq = y0; yq <= y1; ++yq) {
            const float* __restrict__ row = ev + zz * PLANE + yq * DDIM;
            for (int xq = x0; xq <= x1; ++xq) m = fmaxf(m, row[xq]);
        }
    }

    float img;
    if (FIRST) {
        const float* __restrict__ src = (v < HALFV) ? (x + v * VOL) : (y + (v - HALFV) * VOL);
        img = src[r];
    } else {
        img = a[idx];
    }
    float delta = fmaxf(img - m, 0.0f);
    if (FIRST) {
        skel[idx] = delta;
    } else {
        float s = skel[idx];
        float t = delta - s * delta;
        skel[idx] = s + fmaxf(t, 0.0f);
    }
}

__global__ void zero_partials_k(float* __restrict__ p) {
    if (threadIdx.x < 16) p[threadIdx.x] = 0.0f;
}

// per-channel sums: s1=sum(x*cll), s2=sum(cll), s3=sum(clp*y), s4=sum(clp)
__global__ void reduce_k(const float* __restrict__ x, const float* __restrict__ y,
                         const float* __restrict__ skel, float* __restrict__ partials) {
    int idx = blockIdx.x * blockDim.x + threadIdx.x;  // [0, 4*VOL)
    int v = idx / VOL;  // each 256-thread block lies entirely in one volume (VOL % 256 == 0)
    float xv  = x[idx];
    float yv  = y[idx];
    float clp = skel[idx];              // skeleton of x, volume v
    float cll = skel[HALFV * VOL + idx]; // skeleton of y, volume v
    float s1 = xv * cll;
    float s2 = cll;
    float s3 = clp * yv;
    float s4 = clp;

    for (int off = 32; off > 0; off >>= 1) {
        s1 += __shfl_down(s1, off);
        s2 += __shfl_down(s2, off);
        s3 += __shfl_down(s3, off);
        s4 += __shfl_down(s4, off);
    }
    __shared__ float sm[4][4];
    int wave = threadIdx.x >> 6;
    if ((threadIdx.x & 63) == 0) {
        sm[wave][0] = s1; sm[wave][1] = s2; sm[wave][2] = s3; sm[wave][3] = s4;
    }
    __syncthreads();
    if (threadIdx.x == 0) {
        float a0 = 0, a1 = 0, a2 = 0, a3 = 0;
        for (int w = 0; w < 4; ++w) { a0 += sm[w][0]; a1 += sm[w][1]; a2 += sm[w][2]; a3 += sm[w][3]; }
        atomicAdd(&partials[v * 4 + 0], a0);
        atomicAdd(&partials[v * 4 + 1], a1);
        atomicAdd(&partials[v * 4 + 2], a2);
        atomicAdd(&partials[v * 4 + 3], a3);
    }
}

__global__ void final_k(const float* __restrict__ p, float* __restrict__ out) {
    if (threadIdx.x == 0 && blockIdx.x == 0) {
        float acc = 0.0f;
        for (int v = 0; v < 4; ++v) {
            float tp      = p[v * 4 + 0];
            float sum_cll = p[v * 4 + 1];
            float tpc     = p[v * 4 + 2];
            float sum_clp = p[v * 4 + 3];
            float fn  = sum_cll - tp;
            float fpc = sum_clp - tpc;
            float clp2voll = (tpc + 1.0f) / (tpc + fpc + 1.0f);
            float cll2volp = (tp + 1.0f) / (tp + fn + 1.0f);
            float dc = 2.0f * clp2voll * cll2volp / (cll2volp + clp2voll + 1e-8f);
            acc += dc;
        }
        out[0] = 1.0f - acc * 0.25f;
    }
}

extern "C" void kernel_launch(void* const* d_in, const int* in_sizes, int n_in,
                              void* d_out, int out_size, void* d_ws, size_t ws_size,
                              hipStream_t stream) {
    const float* x = (const float*)d_in[0];
    const float* y = (const float*)d_in[1];
    float* out = (float*)d_out;

    float* bufA = (float*)d_ws;
    float* bufB = bufA + NTOT;
    float* skel = bufB + NTOT;
    float* partials = skel + NTOT;

    const int BLK = 256;
    const int GRID = NTOT / BLK;       // 16000
    const int RGRID = (HALFV * VOL) / BLK;  // 8000

    // iteration 0: e = erode(img0); skel = relu(img0 - dilate(e))
    erode_first_k<<<GRID, BLK, 0, stream>>>(x, y, bufA);
    dilate_update_k<true><<<GRID, BLK, 0, stream>>>(x, y, nullptr, bufA, skel);

    // iterations 1..50
    for (int i = 0; i < 50; ++i) {
        erode_step_k<<<GRID, BLK, 0, stream>>>(bufA, bufB);
        dilate_update_k<false><<<GRID, BLK, 0, stream>>>(x, y, bufA, bufB, skel);
        float* t = bufA; bufA = bufB; bufB = t;
    }

    zero_partials_k<<<1, 64, 0, stream>>>(partials);
    reduce_k<<<RGRID, BLK, 0, stream>>>(x, y, skel, partials);
    final_k<<<1, 64, 0, stream>>>(partials, out);
}

// Round 2
// 1478.559 us; speedup vs baseline: 3.2051x; 3.2051x over previous
//
#include <hip/hip_runtime.h>

#define DDIM 80
#define PLANE (DDIM * DDIM)          // 6400
#define VOL   (DDIM * DDIM * DDIM)   // 512000
#define HALFV 4                      // volumes per input (b*c = 2*2)
#define NVOL  8                      // x volumes + y volumes
#define NTOT  (NVOL * VOL)           // 4,096,000

#define TY 8                         // y-rows per block tile
#define CZ 10                        // z-slices per block tile
#define NYT (DDIM / TY)              // 10
#define NZC (DDIM / CZ)              // 8
#define NCHUNK 20                    // float4 chunks per 80-float row

__device__ __forceinline__ float4 f4min(float4 a, float4 b) {
    return make_float4(fminf(a.x, b.x), fminf(a.y, b.y), fminf(a.z, b.z), fminf(a.w, b.w));
}
__device__ __forceinline__ float4 f4max(float4 a, float4 b) {
    return make_float4(fmaxf(a.x, b.x), fmaxf(a.y, b.y), fmaxf(a.z, b.z), fmaxf(a.w, b.w));
}

// One skeletonization iteration, fused: e = erode(img); dil = dilate(e) (from LDS);
// delta = relu(img - dil); skel update. img is x/y (FIRST) or bufA; e written to global.
template <bool FIRST>
__global__ __launch_bounds__(256) void fused_iter_k(const float* __restrict__ xin,
                                                    const float* __restrict__ yin,
                                                    const float* __restrict__ a,
                                                    float* __restrict__ e,
                                                    float* __restrict__ skel) {
    __shared__ float es[3][TY + 2][DDIM];   // rolling erode slices z-1,z,z+1

    const int b = blockIdx.x;
    const int v = b / (NYT * NZC);
    const int rem = b - v * (NYT * NZC);
    const int yt = rem / NZC;
    const int zc = rem - yt * NZC;
    const int y0 = yt * TY;
    const int z0 = zc * CZ;

    const float* __restrict__ src =
        FIRST ? ((v < HALFV) ? (xin + v * VOL) : (yin + (v - HALFV) * VOL))
              : (a + v * VOL);
    float* __restrict__ evol = e + v * VOL;
    const int tid = threadIdx.x;

    const int ery = tid / NCHUNK;          // erode-phase row (0..TY+1)
    const int ecx = tid - ery * NCHUNK;    // chunk (0..19)
    const int dry = tid / NCHUNK;          // dilate-phase row (0..TY-1)
    const int dcx = ecx;

    // ---- erode one z-slice (zs possibly out of [0,80)) into LDS slot (zs+3)%3 ----
    auto erodeSlice = [&](int zs) {
        if (tid < (TY + 2) * NCHUNK) {
            const int zcl = min(max(zs, 0), DDIM - 1);
            const int slot = (zs + 3) % 3;
            const int gy = min(max(y0 - 1 + ery, 0), DDIM - 1);
            const int zm = max(zcl - 1, 0), zp = min(zcl + 1, DDIM - 1);
            const int ym = max(gy - 1, 0), yp = min(gy + 1, DDIM - 1);
            const float* rc = src + zcl * PLANE + gy * DDIM;
            const float4 c  = *(const float4*)(rc + 4 * ecx);
            const float4 zA = *(const float4*)(src + zm * PLANE + gy * DDIM + 4 * ecx);
            const float4 zB = *(const float4*)(src + zp * PLANE + gy * DDIM + 4 * ecx);
            const float4 yA = *(const float4*)(src + zcl * PLANE + ym * DDIM + 4 * ecx);
            const float4 yB = *(const float4*)(src + zcl * PLANE + yp * DDIM + 4 * ecx);
            const float lf = (ecx > 0)  ? rc[4 * ecx - 1] : c.x;
            const float rt = (ecx < 19) ? rc[4 * ecx + 4] : c.w;
            float4 m;
            m.x = fminf(fminf(lf, c.x), c.y);
            m.y = fminf(fminf(c.x, c.y), c.z);
            m.z = fminf(fminf(c.y, c.z), c.w);
            m.w = fminf(fminf(c.z, c.w), rt);
            m = f4min(m, f4min(f4min(zA, zB), f4min(yA, yB)));
            *(float4*)&es[slot][ery][4 * ecx] = m;
            // owned region: rows 1..TY (gy = y0..y0+TY-1), zs in [z0, z0+CZ)
            if (ery >= 1 && ery <= TY && zs >= z0 && zs < z0 + CZ) {
                *(float4*)(evol + zs * PLANE + gy * DDIM + 4 * ecx) = m;
            }
        }
    };

    // ---- dilate(LDS) + skel update at output slice z ----
    auto dilateUpdate = [&](int z) {
        if (tid < TY * NCHUNK) {
            const int gy = y0 + dry;
            float4 vmax = make_float4(-1e30f, -1e30f, -1e30f, -1e30f);
            float lmax = -1e30f, rmax = -1e30f;
#pragma unroll
            for (int s = 0; s < 3; ++s) {
#pragma unroll
                for (int l = 0; l < 3; ++l) {
                    const float* row = &es[s][dry + l][0];
                    const float4 t = *(const float4*)(row + 4 * dcx);
                    vmax = f4max(vmax, t);
                    lmax = fmaxf(lmax, (dcx > 0)  ? row[4 * dcx - 1] : t.x);
                    rmax = fmaxf(rmax, (dcx < 19) ? row[4 * dcx + 4] : t.w);
                }
            }
            float4 dm;
            dm.x = fmaxf(lmax, fmaxf(vmax.x, vmax.y));
            dm.y = fmaxf(vmax.x, fmaxf(vmax.y, vmax.z));
            dm.z = fmaxf(vmax.y, fmaxf(vmax.z, vmax.w));
            dm.w = fmaxf(fmaxf(vmax.z, vmax.w), rmax);

            const int off = v * VOL + z * PLANE + gy * DDIM + 4 * dcx;
            const float4 img = *(const float4*)(src + z * PLANE + gy * DDIM + 4 * dcx);
            float4 delta;
            delta.x = fmaxf(img.x - dm.x, 0.0f);
            delta.y = fmaxf(img.y - dm.y, 0.0f);
            delta.z = fmaxf(img.z - dm.z, 0.0f);
            delta.w = fmaxf(img.w - dm.w, 0.0f);
            if (FIRST) {
                *(float4*)(skel + off) = delta;
            } else {
                float4 s = *(const float4*)(skel + off);
                s.x += fmaxf(delta.x - s.x * delta.x, 0.0f);
                s.y += fmaxf(delta.y - s.y * delta.y, 0.0f);
                s.z += fmaxf(delta.z - s.z * delta.z, 0.0f);
                s.w += fmaxf(delta.w - s.w * delta.w, 0.0f);
                *(float4*)(skel + off) = s;
            }
        }
    };

    erodeSlice(z0 - 1);
    erodeSlice(z0);
    for (int z = z0; z < z0 + CZ; ++z) {
        erodeSlice(z + 1);
        __syncthreads();
        dilateUpdate(z);
        __syncthreads();
    }
}

// 1024 blocks: 256 per volume, each covers 2000 contiguous elements (500 float4).
// Partials written per block (no atomics): partials[blk][4] = {x*cll, cll, clp*y, clp}
__global__ __launch_bounds__(256) void reduce_k(const float* __restrict__ x,
                                                const float* __restrict__ y,
                                                const float* __restrict__ skel,
                                                float* __restrict__ partials) {
    const int blk = blockIdx.x;
    const int v = blk >> 8;               // 256 blocks per volume
    const int sub = blk & 255;
    const int base4 = (v * VOL + sub * 2000) >> 2;   // float4 index

    const float4* x4 = (const float4*)x;
    const float4* y4 = (const float4*)y;
    const float4* clp4 = (const float4*)(skel) + (0) ;            // x-skeleton vol v at v*VOL
    const float4* cll4 = (const float4*)(skel + HALFV * VOL);     // y-skeleton vol v

    float s1 = 0, s2 = 0, s3 = 0, s4 = 0;
    for (int j = threadIdx.x; j < 500; j += 256) {
        const int i4 = base4 + j;
        const float4 xv = x4[i4];
        const float4 yv = y4[i4];
        const float4 cp = clp4[i4];
        const float4 cl = cll4[i4];
        s1 += xv.x * cl.x + xv.y * cl.y + xv.z * cl.z + xv.w * cl.w;
        s2 += cl.x + cl.y + cl.z + cl.w;
        s3 += cp.x * yv.x + cp.y * yv.y + cp.z * yv.z + cp.w * yv.w;
        s4 += cp.x + cp.y + cp.z + cp.w;
    }
    for (int off = 32; off > 0; off >>= 1) {
        s1 += __shfl_down(s1, off);
        s2 += __shfl_down(s2, off);
        s3 += __shfl_down(s3, off);
        s4 += __shfl_down(s4, off);
    }
    __shared__ float sm[4][4];
    const int wave = threadIdx.x >> 6;
    if ((threadIdx.x & 63) == 0) {
        sm[wave][0] = s1; sm[wave][1] = s2; sm[wave][2] = s3; sm[wave][3] = s4;
    }
    __syncthreads();
    if (threadIdx.x == 0) {
        float a0 = 0, a1 = 0, a2 = 0, a3 = 0;
        for (int w = 0; w < 4; ++w) { a0 += sm[w][0]; a1 += sm[w][1]; a2 += sm[w][2]; a3 += sm[w][3]; }
        partials[blk * 4 + 0] = a0;
        partials[blk * 4 + 1] = a1;
        partials[blk * 4 + 2] = a2;
        partials[blk * 4 + 3] = a3;
    }
}

__global__ void final_k(const float* __restrict__ p, float* __restrict__ out) {
    __shared__ float sums[16];
    const int t = threadIdx.x;
    if (t < 16) {
        const int v = t >> 2, k = t & 3;
        float acc = 0.0f;
        for (int b = 0; b < 256; ++b) acc += p[((v << 8) + b) * 4 + k];
        sums[t] = acc;
    }
    __syncthreads();
    if (t == 0) {
        float acc = 0.0f;
        for (int v = 0; v < 4; ++v) {
            const float tp      = sums[v * 4 + 0];
            const float sum_cll = sums[v * 4 + 1];
            const float tpc     = sums[v * 4 + 2];
            const float sum_clp = sums[v * 4 + 3];
            const float fn  = sum_cll - tp;
            const float fpc = sum_clp - tpc;
            const float clp2voll = (tpc + 1.0f) / (tpc + fpc + 1.0f);
            const float cll2volp = (tp + 1.0f) / (tp + fn + 1.0f);
            const float dc = 2.0f * clp2voll * cll2volp / (cll2volp + clp2voll + 1e-8f);
            acc += dc;
        }
        out[0] = 1.0f - acc * 0.25f;
    }
}

extern "C" void kernel_launch(void* const* d_in, const int* in_sizes, int n_in,
                              void* d_out, int out_size, void* d_ws, size_t ws_size,
                              hipStream_t stream) {
    const float* x = (const float*)d_in[0];
    const float* y = (const float*)d_in[1];
    float* out = (float*)d_out;

    float* bufA = (float*)d_ws;
    float* bufB = bufA + NTOT;
    float* skel = bufB + NTOT;
    float* partials = skel + NTOT;   // 1024*4 floats

    const int GRID = NVOL * NYT * NZC;   // 640
    const int BLK = 256;

    // iteration 0: bufA = erode(img0); skel = relu(img0 - dilate(bufA))
    fused_iter_k<true><<<GRID, BLK, 0, stream>>>(x, y, nullptr, bufA, skel);

    // iterations 1..50
    for (int i = 0; i < 50; ++i) {
        fused_iter_k<false><<<GRID, BLK, 0, stream>>>(nullptr, nullptr, bufA, bufB, skel);
        float* t = bufA; bufA = bufB; bufB = t;
    }

    reduce_k<<<1024, BLK, 0, stream>>>(x, y, skel, partials);
    final_k<<<1, 64, 0, stream>>>(partials, out);
}